// Round 1
// baseline (292.348 us; speedup 1.0000x reference)
//
#include <hip/hip_runtime.h>
#include <stdint.h>

typedef unsigned short us16;
typedef unsigned short us8  __attribute__((ext_vector_type(8)));
typedef unsigned short us4v __attribute__((ext_vector_type(4)));
typedef __bf16         bf16x8 __attribute__((ext_vector_type(8)));
typedef float          f32x4  __attribute__((ext_vector_type(4)));

__device__ __forceinline__ us16 f2bf(float f) {
    union { float f; unsigned int u; } c; c.f = f;
    unsigned int u = (c.u + 0x7fffu + ((c.u >> 16) & 1u)) >> 16;
    return (us16)u;
}
__device__ __forceinline__ float bf2f(us16 h) {
    union { unsigned int u; float f; } c; c.u = ((unsigned int)h) << 16;
    return c.f;
}

// ---------------------------------------------------------------------------
// K0a: x [B][D][S] fp32  ->  XT [B][S][D] bf16   (64x64 LDS tile transpose)
// ---------------------------------------------------------------------------
__global__ __launch_bounds__(256)
void transpose_x(const float* __restrict__ x, us16* __restrict__ xt) {
    const int b = blockIdx.z, d0 = blockIdx.y * 64, s0 = blockIdx.x * 64;
    __shared__ us16 tile[64 * 65];
    const float* xp = x + ((size_t)b * 1024 + d0) * 2048 + s0;
    const int t = threadIdx.x;
    const int r = t >> 4;      // d within 16-row group
    const int c4 = t & 15;     // s group (4 wide)
#pragma unroll
    for (int i = 0; i < 4; i++) {
        float4 v = *(const float4*)(xp + (size_t)(r + 16 * i) * 2048 + c4 * 4);
        const int d = r + 16 * i;
        tile[(c4 * 4 + 0) * 65 + d] = f2bf(v.x);
        tile[(c4 * 4 + 1) * 65 + d] = f2bf(v.y);
        tile[(c4 * 4 + 2) * 65 + d] = f2bf(v.z);
        tile[(c4 * 4 + 3) * 65 + d] = f2bf(v.w);
    }
    __syncthreads();
    us16* op = xt + ((size_t)b * 2048 + s0) * 1024 + d0;
#pragma unroll
    for (int i = 0; i < 2; i++) {
        const int u = t + 256 * i;     // 0..511
        const int s = u >> 3, c8 = u & 7;
        us8 o;
#pragma unroll
        for (int j = 0; j < 8; j++) o[j] = tile[s * 65 + c8 * 8 + j];
        *(us8*)(op + (size_t)s * 1024 + c8 * 8) = o;
    }
}

// ---------------------------------------------------------------------------
// K0b: Wq,Wk,Wv fp32 -> Wb bf16 [3][1024][1024]
// ---------------------------------------------------------------------------
__global__ __launch_bounds__(256)
void convert_w(const float* __restrict__ wq, const float* __restrict__ wk,
               const float* __restrict__ wv, us16* __restrict__ wb) {
    const int mb = blockIdx.x >> 10;  // 1024 blocks per matrix
    const float* src = (mb == 0) ? wq : (mb == 1) ? wk : wv;
    const size_t off = ((size_t)(blockIdx.x & 1023) * 256 + threadIdx.x) * 4;
    float4 v = *(const float4*)(src + off);
    us4v o = { f2bf(v.x), f2bf(v.y), f2bf(v.z), f2bf(v.w) };
    *(us4v*)(wb + (size_t)mb * 1048576 + off) = o;
}

// ---------------------------------------------------------------------------
// NT bf16 GEMM:  C[n][m] = sum_k A[m][k]*B[n][k] (+bias)
// A: [M][K] bf16 (k-contig), B: [N][K] bf16 (k-contig), C: [N][M]
// OUT_F32: store fp32, else bf16.  BIAS: 0 none, 1 bias[m] (f4), 2 bias[n].
// 128x128 block tile, BK=64, 4 waves 2x2, 4x4 tiles of mfma 16x16x32 bf16.
// ---------------------------------------------------------------------------
template <bool OUT_F32, int BIAS>
__global__ __launch_bounds__(256, 2)
void gemm_bt(const us16* __restrict__ A, long long strideA,
             const us16* __restrict__ B, long long strideB,
             void* __restrict__ C, long long strideC,
             const float* __restrict__ bias,
             int M, int N, int K) {
    const int bz = blockIdx.z;
    A += (size_t)strideA * bz;
    B += (size_t)strideB * bz;
    const int m0 = blockIdx.x * 128, n0 = blockIdx.y * 128;

    __shared__ us16 lsA[128 * 72];
    __shared__ us16 lsB[128 * 72];

    const int tid = threadIdx.x;
    const int lane = tid & 63, wid = tid >> 6;
    const int l15 = lane & 15, quad = lane >> 4;
    const int wm = (wid & 1) * 64, wn = (wid >> 1) * 64;

    f32x4 acc[4][4] = {};

    const int srow = tid >> 3;   // 0..31
    const int sc8 = tid & 7;     // 16B unit in 64-half k-chunk
    const us16* Ap = A + (size_t)(m0 + srow) * K + sc8 * 8;
    const us16* Bp = B + (size_t)(n0 + srow) * K + sc8 * 8;

    for (int kb = 0; kb < K; kb += 64) {
        us8 va[4], vb[4];
#pragma unroll
        for (int i = 0; i < 4; i++) {
            va[i] = *(const us8*)(Ap + kb + (size_t)(32 * i) * K);
            vb[i] = *(const us8*)(Bp + kb + (size_t)(32 * i) * K);
        }
        __syncthreads();   // prev iter's frag reads done before overwrite
#pragma unroll
        for (int i = 0; i < 4; i++) {
            *(us8*)(&lsA[(srow + 32 * i) * 72 + sc8 * 8]) = va[i];
            *(us8*)(&lsB[(srow + 32 * i) * 72 + sc8 * 8]) = vb[i];
        }
        __syncthreads();
#pragma unroll
        for (int ks = 0; ks < 2; ks++) {
            bf16x8 af[4], bfr[4];
#pragma unroll
            for (int i = 0; i < 4; i++) {
                af[i]  = *(const bf16x8*)(&lsA[(wm + i * 16 + l15) * 72 + ks * 32 + quad * 8]);
                bfr[i] = *(const bf16x8*)(&lsB[(wn + i * 16 + l15) * 72 + ks * 32 + quad * 8]);
            }
#pragma unroll
            for (int i = 0; i < 4; i++)
#pragma unroll
                for (int j = 0; j < 4; j++)
                    acc[i][j] = __builtin_amdgcn_mfma_f32_16x16x32_bf16(af[i], bfr[j], acc[i][j], 0, 0, 0);
        }
    }

    const size_t cbase = (size_t)strideC * bz;
#pragma unroll
    for (int i = 0; i < 4; i++) {
        const int mb = m0 + wm + i * 16 + quad * 4;
        float b0 = 0.f, b1 = 0.f, b2 = 0.f, b3 = 0.f;
        if (BIAS == 1) {
            float4 bv4 = *(const float4*)(bias + mb);
            b0 = bv4.x; b1 = bv4.y; b2 = bv4.z; b3 = bv4.w;
        }
#pragma unroll
        for (int j = 0; j < 4; j++) {
            const int n = n0 + wn + j * 16 + l15;
            const float bn = (BIAS == 2) ? bias[n] : 0.0f;
            f32x4 v = acc[i][j];
            const float o0 = v[0] + b0 + bn, o1 = v[1] + b1 + bn;
            const float o2 = v[2] + b2 + bn, o3 = v[3] + b3 + bn;
            if (OUT_F32) {
                float4 st; st.x = o0; st.y = o1; st.z = o2; st.w = o3;
                *(float4*)((float*)C + cbase + (size_t)n * M + mb) = st;
            } else {
                us4v st = { f2bf(o0), f2bf(o1), f2bf(o2), f2bf(o3) };
                *(us4v*)((us16*)C + cbase + (size_t)n * M + mb) = st;
            }
        }
    }
}

// ---------------------------------------------------------------------------
// K2b: in-place row softmax over S [B*S rows][2048] bf16, scale = 1/sqrt(D)
// ---------------------------------------------------------------------------
__global__ __launch_bounds__(256)
void softmax_inplace(us16* __restrict__ S) {
    const float scale = 0.03125f;  // 1/32
    us16* p = S + (size_t)blockIdx.x * 2048;
    const int t = threadIdx.x;
    us8 v = *(const us8*)(p + t * 8);
    float x[8];
#pragma unroll
    for (int i = 0; i < 8; i++) x[i] = bf2f(v[i]) * scale;

    float m = x[0];
#pragma unroll
    for (int i = 1; i < 8; i++) m = fmaxf(m, x[i]);
#pragma unroll
    for (int off = 1; off < 64; off <<= 1) m = fmaxf(m, __shfl_xor(m, off, 64));
    __shared__ float red[4];
    __shared__ float red2[4];
    if ((t & 63) == 0) red[t >> 6] = m;
    __syncthreads();
    m = fmaxf(fmaxf(red[0], red[1]), fmaxf(red[2], red[3]));

    float s = 0.f;
#pragma unroll
    for (int i = 0; i < 8; i++) { x[i] = __expf(x[i] - m); s += x[i]; }
#pragma unroll
    for (int off = 1; off < 64; off <<= 1) s += __shfl_xor(s, off, 64);
    if ((t & 63) == 0) red2[t >> 6] = s;
    __syncthreads();
    s = red2[0] + red2[1] + red2[2] + red2[3];
    const float inv = 1.0f / s;

    us8 o;
#pragma unroll
    for (int i = 0; i < 8; i++) o[i] = f2bf(x[i] * inv);
    *(us8*)(p + t * 8) = o;
}

// ---------------------------------------------------------------------------
extern "C" void kernel_launch(void* const* d_in, const int* in_sizes, int n_in,
                              void* d_out, int out_size, void* d_ws, size_t ws_size,
                              hipStream_t stream) {
    const float* x  = (const float*)d_in[0];
    const float* Wq = (const float*)d_in[1];
    const float* bq = (const float*)d_in[2];
    const float* Wk = (const float*)d_in[3];
    const float* bk = (const float*)d_in[4];
    const float* Wv = (const float*)d_in[5];
    const float* bv = (const float*)d_in[6];
    float* out = (float*)d_out;
    char* ws = (char*)d_ws;

    // B=4, S=2048, D=1024.  B*S*D bf16 = 16 MiB per tensor.
    const size_t SZ = 16777216;
    us16* Qb = (us16*)(ws);
    us16* Kb = (us16*)(ws + SZ);
    us16* VT = (us16*)(ws + 2 * SZ);            // [B][D][S] (v transposed)
    us16* XT = (us16*)(ws + 3 * SZ);            // [B][S][D]
    us16* Wb = (us16*)(ws + 4 * SZ);            // [3][1024][1024]
    us16* Sb = (us16*)(ws + 3 * SZ);            // scores/P [B][S][S]; aliases XT+Wb (dead)
    // total ws use: 5*16MiB + ... = 84 MB (Sb spans [48MiB, 80MiB))

    const long long sXT = 2097152;   // S*D
    const long long sSS = 4194304;   // S*S
    dim3 blk(256, 1, 1);

    transpose_x<<<dim3(32, 16, 4), blk, 0, stream>>>(x, XT);
    convert_w<<<dim3(3072, 1, 1), blk, 0, stream>>>(Wq, Wk, Wv, Wb);

    // Q[b][s][e]: A=Wq (m=e), B=XT (n=s), bias over m
    gemm_bt<false, 1><<<dim3(8, 16, 4), blk, 0, stream>>>(
        Wb, 0LL, XT, sXT, (void*)Qb, sXT, bq, 1024, 2048, 1024);
    gemm_bt<false, 1><<<dim3(8, 16, 4), blk, 0, stream>>>(
        Wb + 1048576, 0LL, XT, sXT, (void*)Kb, sXT, bk, 1024, 2048, 1024);
    // VT[b][e][s]: A=XT (m=s), B=Wv (n=e), bias over n
    gemm_bt<false, 2><<<dim3(16, 8, 4), blk, 0, stream>>>(
        XT, sXT, Wb + 2097152, 0LL, (void*)VT, sXT, bv, 2048, 1024, 1024);

    // scores S[b][s][t] = q_s . k_t : A=K (m=t), B=Q (n=s)
    gemm_bt<false, 0><<<dim3(16, 16, 4), blk, 0, stream>>>(
        Kb, sXT, Qb, sXT, (void*)Sb, sSS, nullptr, 2048, 2048, 1024);

    softmax_inplace<<<dim3(8192, 1, 1), blk, 0, stream>>>(Sb);

    // out[b][s][e] = sum_t P[s][t] * v[t][e] : A=VT (m=e), B=P (n=s), fp32 out
    gemm_bt<true, 0><<<dim3(8, 16, 4), blk, 0, stream>>>(
        VT, sXT, Sb, sSS, (void*)out, sXT, nullptr, 1024, 2048, 2048);
}